// Round 8
// baseline (1238.515 us; speedup 1.0000x reference)
//
#include <hip/hip_runtime.h>
#include <hip/hip_bf16.h>

#define NTH     1024
#define NSTEPS  100
#define PITERS  50
#define LAMBDAV 0.1f

typedef __bf16 bf16x8 __attribute__((ext_vector_type(8)));
typedef float  f32x4  __attribute__((ext_vector_type(4)));

// LDS map — audited, non-overlapping, 147456 B total (1 block/CU):
//   yF  fp32 [64][256]        @0       (65536 B)  stride 1024  (wst overlay during init)
//   wtl bf16 W-lo^T [64][256] @65536   (32768 B)  stride 512   (phase-1 B-lo)
//   whb bf16 W-hi  [256][64]  @98304   (32768 B)  stride 128   (phase-2 B-hi)
//   rhb bf16 R-hi  [64][64]   @131072  (8192 B)   stride 128
//   rlb bf16 R-lo  [64][64]   @139264  (8192 B)   stride 128
// R8 change: 16 waves (1024 thr), 1 p1-tile + 4 p2-tiles per wave ->
// persistent regs ~92 (wbh 32 + w2lo 32 + xm 16 + nin 4) so 128-VGPR /
// 4-waves-per-EU occupancy is reachable (R7 was latency-bound at 2/EU).

__global__ __launch_bounds__(NTH, 4)
void fista8(const float* __restrict__ inp, const float* __restrict__ Wg,
            const float* __restrict__ X0, float* __restrict__ out)
{
    __shared__ __align__(16) char lds[147456];
    __shared__ __align__(16) float vf[256];
    __shared__ __align__(16) float up[256];
    __shared__ __align__(16) float uf[64];
    __shared__ float red[16];
    __shared__ float scal[2];

    char* const yF  = lds;
    char* const wtl = lds + 65536;
    char* const whb = lds + 98304;
    char* const rhb = lds + 131072;
    char* const rlb = lds + 139264;
    char* const wst = lds;            // fp32 W staging overlay on yF

    const int tid  = threadIdx.x;
    const int w    = tid >> 6;        // 0..15
    const int lane = tid & 63;
    const int l4   = lane >> 4;
    const int ln   = lane & 15;
    const int rb   = blockIdx.x * 64;

    const int mi = w >> 2;            // 0..3  m-tile (both phases)
    const int nw = w & 3;             // 0..3  phase-1 n-tile; phase-2 n-quarter

    // ---- stage W fp32 (swizzled) ----
    #pragma unroll
    for (int i = 0; i < 4; ++i) {
        int wi = (tid + i * NTH) * 4; int j = wi >> 6, k = wi & 63;
        f32x4 v = *(const f32x4*)&Wg[wi];
        *(f32x4*)(wst + j * 256 + ((k * 4) ^ ((j & 7) << 4))) = v;
    }
    // ---- bf16 planes: W-hi row-major + W-lo transposed ----
    for (int i = tid; i < 256 * 64; i += NTH) {
        int j = i >> 6, k = i & 63;
        float wv = Wg[i];
        __bf16 h = (__bf16)wv;
        __bf16 l = (__bf16)(wv - (float)h);
        *(__bf16*)(whb + j * 128 + ((k * 2) ^ ((j & 7) << 4))) = h;
        *(__bf16*)(wtl + k * 512 + ((j * 2) ^ ((k & 7) << 4))) = l;
    }

    // ---- per-thread constants ----
    float nin[4];
    #pragma unroll
    for (int r = 0; r < 4; ++r)
        nin[r] = -inp[(size_t)(rb + mi * 16 + 4 * l4 + r) * 64 + nw * 16 + ln];

    float xm[4][4];
    #pragma unroll
    for (int q = 0; q < 4; ++q)
        #pragma unroll
        for (int r = 0; r < 4; ++r)
            xm[q][r] = X0[(size_t)(rb + mi * 16 + 4 * l4 + r) * 256 + (4 * nw + q) * 16 + ln];

    if (tid < 256) vf[tid] = 0.0625f;
    __syncthreads();

    // ---- Lipschitz: 50 power iterations of Q = 2 W W^T (R2-verified) ----
    for (int it = 0; it <= PITERS; ++it) {
        if (tid < 256) {
            int col = tid & 63, jq = tid >> 6;
            float s = 0.f;
            #pragma unroll 4
            for (int j = jq * 64; j < jq * 64 + 64; ++j)
                s += vf[j] * *(const float*)(wst + j * 256 + ((col * 4) ^ ((j & 7) << 4)));
            up[tid] = s;
        }
        __syncthreads();
        if (tid < 64) uf[tid] = up[tid] + up[tid + 64] + up[tid + 128] + up[tid + 192];
        __syncthreads();
        float w2 = 0.f;
        if (tid < 256) {
            float s = 0.f;
            #pragma unroll
            for (int kc = 0; kc < 64; kc += 4) {
                f32x4 wv = *(const f32x4*)(wst + tid * 256 + ((kc * 4) ^ ((tid & 7) << 4)));
                f32x4 u4 = *(const f32x4*)&uf[kc];
                s += wv.x * u4.x + wv.y * u4.y + wv.z * u4.z + wv.w * u4.w;
            }
            w2 = 2.f * s;
        }
        float sq = (tid < 256) ? ((it == PITERS) ? vf[tid] * w2 : w2 * w2) : 0.f;
        #pragma unroll
        for (int off = 32; off >= 1; off >>= 1) sq += __shfl_down(sq, off);
        if (tid < 256 && lane == 0) red[tid >> 6] = sq;
        __syncthreads();
        float tot = red[0] + red[1] + red[2] + red[3];
        if (it < PITERS) { if (tid < 256) vf[tid] = w2 * (1.f / sqrtf(tot)); }
        else if (tid == 0) { scal[0] = 1.f / tot; scal[1] = LAMBDAV / tot; }
        __syncthreads();
    }
    const float c2  = 2.f * scal[0];
    const float thr = scal[1];

    // ---- phase-1 W-hi fragments -> registers (8 frags = 32 VGPR) ----
    bf16x8 wbh[8];
    {
        const int col4 = (nw * 16 + ln) * 4;
        #pragma unroll
        for (int c = 0; c < 8; ++c) {
            bf16x8 p{};
            #pragma unroll
            for (int t = 0; t < 8; ++t) {
                int j = c * 32 + 8 * l4 + t;
                p[t] = (__bf16)(*(const float*)(wst + j * 256 + (col4 ^ ((j & 7) << 4))));
            }
            wbh[c] = p;
        }
    }
    // ---- phase-2 W-lo fragments -> registers (8 frags = 32 VGPR) ----
    bf16x8 w2lo[4][2];
    #pragma unroll
    for (int q = 0; q < 4; ++q) {
        const int brow = (4 * nw + q) * 16 + ln;
        #pragma unroll
        for (int c = 0; c < 2; ++c) {
            bf16x8 p{};
            #pragma unroll
            for (int t = 0; t < 8; ++t) {
                int k = c * 32 + 8 * l4 + t;
                float wv = *(const float*)(wst + brow * 256 + ((k * 4) ^ ((brow & 7) << 4)));
                __bf16 h = (__bf16)wv;
                p[t] = (__bf16)(wv - (float)h);
            }
            w2lo[q][c] = p;
        }
    }
    __syncthreads();   // all wst consumers done; yF region free

    // ---- y0 = X0 into fp32 LDS ----
    #pragma unroll
    for (int q = 0; q < 4; ++q)
        #pragma unroll
        for (int r = 0; r < 4; ++r) {
            int row = mi * 16 + 4 * l4 + r;
            int col = (4 * nw + q) * 16 + ln;
            *(float*)(yF + row * 1024 + ((col * 4) ^ ((row & 7) << 4))) = xm[q][r];
        }
    __syncthreads();

    const int arow = mi * 16 + ln;
    const int ax   = (arow & 7) << 4;
    const int b0   = nw * 16 + ln;            // wtl row (phase-1 B-lo)
    const int bx   = (ln & 7) << 4;

    float tt = 1.f;
    for (int step = 0; step < NSTEPS; ++step) {
        // ======== phase 1: R = y W - in  (one 16x16 tile per wave) ========
        f32x4 a0 = { nin[0], nin[1], nin[2], nin[3] };
        #pragma unroll
        for (int c = 0; c < 8; ++c) {
            const int lb = c * 128 + l4 * 32;
            f32x4 v0 = *(const f32x4*)(yF + arow * 1024 + (lb ^ ax));
            f32x4 v1 = *(const f32x4*)(yF + arow * 1024 + ((lb + 16) ^ ax));
            bf16x8 ah{}, al{};
            #pragma unroll
            for (int t = 0; t < 4; ++t) {
                float f = v0[t];
                __bf16 h = (__bf16)f;
                ah[t] = h;
                al[t] = (__bf16)(f - (float)h);
            }
            #pragma unroll
            for (int t = 0; t < 4; ++t) {
                float f = v1[t];
                __bf16 h = (__bf16)f;
                ah[4 + t] = h;
                al[4 + t] = (__bf16)(f - (float)h);
            }
            const int kb = c * 64 + l4 * 16;
            bf16x8 bl = *(const bf16x8*)(wtl + b0 * 512 + (kb ^ bx));
            a0 = __builtin_amdgcn_mfma_f32_16x16x32_bf16(ah, wbh[c], a0, 0, 0, 0);
            a0 = __builtin_amdgcn_mfma_f32_16x16x32_bf16(al, wbh[c], a0, 0, 0, 0);
            a0 = __builtin_amdgcn_mfma_f32_16x16x32_bf16(ah, bl,     a0, 0, 0, 0);
        }
        #pragma unroll
        for (int r = 0; r < 4; ++r) {
            int row = mi * 16 + 4 * l4 + r;
            int off = row * 128 + (((nw * 16 + ln) * 2) ^ ((row & 7) << 4));
            float v = a0[r];
            __bf16 h = (__bf16)v;
            *(__bf16*)(rhb + off) = h;
            *(__bf16*)(rlb + off) = (__bf16)(v - (float)h);
        }
        __syncthreads();

        // ======== phase 2: g = R W^T  (four 16x16 tiles per wave) ========
        f32x4 g2[4];
        #pragma unroll
        for (int q = 0; q < 4; ++q) g2[q] = (f32x4){0.f, 0.f, 0.f, 0.f};
        {
            const int r0 = mi * 16 + ln;
            const int rx = (ln & 7) << 4;
            #pragma unroll
            for (int c = 0; c < 2; ++c) {
                const int kb = c * 64 + l4 * 16;
                bf16x8 rh = *(const bf16x8*)(rhb + r0 * 128 + (kb ^ rx));
                bf16x8 rl = *(const bf16x8*)(rlb + r0 * 128 + (kb ^ rx));
                #pragma unroll
                for (int q = 0; q < 4; ++q) {
                    const int brow = (4 * nw + q) * 16 + ln;
                    bf16x8 bh = *(const bf16x8*)(whb + brow * 128 + (kb ^ rx));
                    g2[q] = __builtin_amdgcn_mfma_f32_16x16x32_bf16(rh, bh,         g2[q], 0, 0, 0);
                    g2[q] = __builtin_amdgcn_mfma_f32_16x16x32_bf16(rl, bh,         g2[q], 0, 0, 0);
                    g2[q] = __builtin_amdgcn_mfma_f32_16x16x32_bf16(rh, w2lo[q][c], g2[q], 0, 0, 0);
                }
            }
        }

        // ======== update: prox + momentum; y read from + written to LDS ========
        const float t2v = 0.5f + 0.5f * sqrtf(1.f + 4.f * tt * tt);
        const float mom = (tt - 1.f) / t2v;
        tt = t2v;
        #pragma unroll
        for (int q = 0; q < 4; ++q)
            #pragma unroll
            for (int r = 0; r < 4; ++r) {
                int row = mi * 16 + 4 * l4 + r;
                int col = (4 * nw + q) * 16 + ln;
                float* yp = (float*)(yF + row * 1024 + ((col * 4) ^ ((row & 7) << 4)));
                float yv = *yp;                      // own cell — race-free
                float u  = yv - c2 * g2[q][r];
                float x2 = fmaxf(u - thr, 0.f) + fminf(u + thr, 0.f);
                float yn = x2 + mom * (x2 - xm[q][r]);
                xm[q][r] = x2;
                *yp = yn;
            }
        __syncthreads();
    }

    // ---- store X ----
    #pragma unroll
    for (int q = 0; q < 4; ++q)
        #pragma unroll
        for (int r = 0; r < 4; ++r)
            out[(size_t)(rb + mi * 16 + 4 * l4 + r) * 256 + (4 * nw + q) * 16 + ln] = xm[q][r];
}

extern "C" void kernel_launch(void* const* d_in, const int* in_sizes, int n_in,
                              void* d_out, int out_size, void* d_ws, size_t ws_size,
                              hipStream_t stream) {
    (void)in_sizes; (void)n_in; (void)d_ws; (void)ws_size; (void)out_size;
    const float* inp = (const float*)d_in[0];   // [16384, 64]
    const float* Wg  = (const float*)d_in[1];   // [256, 64]
    const float* X0  = (const float*)d_in[2];   // [16384, 256]
    float* outp      = (float*)d_out;           // [16384, 256]
    fista8<<<16384 / 64, NTH, 0, stream>>>(inp, Wg, X0, outp);
}

// Round 9
// 551.937 us; speedup vs baseline: 2.2439x; 2.2439x over previous
//
#include <hip/hip_runtime.h>
#include <hip/hip_bf16.h>

#define NTH     512
#define NSTEPS  100
#define PITERS  50
#define LAMBDAV 0.1f

typedef __bf16 bf16x8 __attribute__((ext_vector_type(8)));
typedef float  f32x4  __attribute__((ext_vector_type(4)));

__device__ __forceinline__ unsigned short f2bf(float x) {
    unsigned int u = __builtin_bit_cast(unsigned int, x);
    unsigned int r = (u + 0x7FFFu + ((u >> 16) & 1u)) >> 16;   // RNE
    return (unsigned short)r;
}
__device__ __forceinline__ float bf2f(unsigned short h) {
    unsigned int u = ((unsigned int)h) << 16;
    return __builtin_bit_cast(float, u);
}

// R9 = R2 champion (566us) + R7's p2 tile mapping (B-redundancy 4x -> 2x).
// LDS map (identical to R2, 147456 B):
//   yh [64][256] bf16 @0      stride 512   yl @32768
//   whb[256][64] bf16 @65536  stride 128   wlb @98304
//   rhb[64][64]  bf16 @131072 stride 128   rlb @139264
//   wst fp32 [256][64] stride 256 overlays yh/yl during init.
// Persistent regs = 136 (wbh 32 + wbl 32 + xm 32 + ym 32 + nin 8) — the
// R2-proven no-spill budget at the immovable 128-VGPR cap (cap ~= 65536/NTH).

__global__ __launch_bounds__(NTH, 2)
void fista9(const float* __restrict__ inp, const float* __restrict__ Wg,
            const float* __restrict__ X0, float* __restrict__ out)
{
    __shared__ __align__(16) char lds[147456];
    __shared__ __align__(16) float vf[256];
    __shared__ __align__(16) float up[256];
    __shared__ __align__(16) float uf[64];
    __shared__ float red[16];
    __shared__ float scal[2];

    char* const yhb = lds;
    char* const ylb = lds + 32768;
    char* const whb = lds + 65536;
    char* const wlb = lds + 98304;
    char* const rhb = lds + 131072;
    char* const rlb = lds + 139264;
    char* const wst = lds;            // fp32 staging overlay

    const int tid  = threadIdx.x;
    const int w    = tid >> 6;
    const int lane = tid & 63;
    const int l4   = lane >> 4;       // 0..3
    const int ln   = lane & 15;       // 0..15
    const int rb   = blockIdx.x * 64;

    // phase-1 (R2): wave -> n-tile nw, m-tiles {mw0, mw0+1}
    const int nw  = w & 3;
    const int mw0 = (w >> 2) * 2;
    // phase-2 (R7 mapping): wave -> m-tiles {2mp,2mp+1}, n-tiles {4nq..4nq+3}
    const int mp = w >> 2;            // 0..1
    const int nq = w & 3;             // 0..3

    // ---- stage W fp32 into LDS (swizzled) + bf16 hi/lo planes ----
    #pragma unroll
    for (int i = 0; i < 8; ++i) {
        int wi = (tid + i * NTH) * 4;
        int j = wi >> 6, k = wi & 63;
        f32x4 v = *(const f32x4*)&Wg[wi];
        *(f32x4*)(wst + j * 256 + ((k * 4) ^ ((j & 7) << 4))) = v;
    }
    for (int i = tid; i < 256 * 64; i += NTH) {
        int j = i >> 6, k = i & 63;
        float wv = Wg[i];
        unsigned short h = f2bf(wv);
        int off = j * 128 + ((k * 2) ^ ((j & 7) << 4));
        *(unsigned short*)(whb + off) = h;
        *(unsigned short*)(wlb + off) = f2bf(wv - bf2f(h));
    }

    // ---- per-thread constants ----
    float nin[2][4];                           // -in, phase-1 D layout
    #pragma unroll
    for (int s = 0; s < 2; ++s)
        #pragma unroll
        for (int r = 0; r < 4; ++r)
            nin[s][r] = -inp[(size_t)(rb + (mw0 + s) * 16 + l4 * 4 + r) * 64 + nw * 16 + ln];

    float xm[2][4][4], ym[2][4][4];            // X, y masters, phase-2 D layout
    #pragma unroll
    for (int s = 0; s < 2; ++s)
      #pragma unroll
      for (int q = 0; q < 4; ++q)
        #pragma unroll
        for (int r = 0; r < 4; ++r) {
            float v = X0[(size_t)(rb + (2 * mp + s) * 16 + l4 * 4 + r) * 256 + (4 * nq + q) * 16 + ln];
            xm[s][q][r] = v; ym[s][q][r] = v;
        }

    if (tid < 256) vf[tid] = 0.0625f;          // ones/sqrt(256)
    __syncthreads();

    // ---- Lipschitz: 50 power iterations of Q = 2 W W^T (R2-verified) ----
    for (int it = 0; it <= PITERS; ++it) {
        if (tid < 256) {                       // partial u = W^T v (4-way j split)
            int col = tid & 63, jq = tid >> 6;
            float s = 0.f;
            #pragma unroll 4
            for (int j = jq * 64; j < jq * 64 + 64; ++j)
                s += vf[j] * *(const float*)(wst + j * 256 + ((col * 4) ^ ((j & 7) << 4)));
            up[tid] = s;
        }
        __syncthreads();
        if (tid < 64) uf[tid] = up[tid] + up[tid + 64] + up[tid + 128] + up[tid + 192];
        __syncthreads();
        float w2 = 0.f;
        if (tid < 256) {                       // w2 = 2 * W[tid,:] . u
            float s = 0.f;
            #pragma unroll
            for (int kc = 0; kc < 64; kc += 4) {
                f32x4 wv = *(const f32x4*)(wst + tid * 256 + ((kc * 4) ^ ((tid & 7) << 4)));
                f32x4 u4 = *(const f32x4*)&uf[kc];
                s += wv.x * u4.x + wv.y * u4.y + wv.z * u4.z + wv.w * u4.w;
            }
            w2 = 2.f * s;
        }
        float sq = (tid < 256) ? ((it == PITERS) ? vf[tid] * w2 : w2 * w2) : 0.f;
        #pragma unroll
        for (int off = 32; off >= 1; off >>= 1) sq += __shfl_down(sq, off);
        if (tid < 256 && lane == 0) red[tid >> 6] = sq;
        __syncthreads();
        float tot = red[0] + red[1] + red[2] + red[3];
        if (it < PITERS) {
            if (tid < 256) vf[tid] = w2 * (1.f / sqrtf(tot));
        } else if (tid == 0) {
            scal[0] = 1.f / tot;               // invL (Rayleigh quotient)
            scal[1] = LAMBDAV / tot;           // thr
        }
        __syncthreads();
    }

    // ---- phase-1 B fragments (W columns nw*16..+15, K=256) -> registers ----
    bf16x8 wbh[8], wbl[8];
    #pragma unroll
    for (int c = 0; c < 8; ++c) {
        union { unsigned short u[8]; bf16x8 v; } ph, pl;
        #pragma unroll
        for (int tt = 0; tt < 8; ++tt) {
            int j = 32 * c + 8 * l4 + tt;
            float wv = *(const float*)(wst + j * 256 + (((nw * 16 + ln) * 4) ^ ((j & 7) << 4)));
            unsigned short h = f2bf(wv);
            ph.u[tt] = h; pl.u[tt] = f2bf(wv - bf2f(h));
        }
        wbh[c] = ph.v; wbl[c] = pl.v;
    }
    __syncthreads();   // done with fp32 W staging; y region is now free

    // ---- y0 = X0 into LDS (bf16 hi/lo) ----
    #pragma unroll
    for (int s = 0; s < 2; ++s)
      #pragma unroll
      for (int q = 0; q < 4; ++q)
        #pragma unroll
        for (int r = 0; r < 4; ++r) {
            int row = (2 * mp + s) * 16 + l4 * 4 + r;
            int cb  = ((4 * nq + q) * 16 + ln) * 2;
            int off = row * 512 + (cb ^ ((row & 7) << 4));
            unsigned short h = f2bf(ym[s][q][r]);
            *(unsigned short*)(yhb + off) = h;
            *(unsigned short*)(ylb + off) = f2bf(ym[s][q][r] - bf2f(h));
        }
    __syncthreads();

    const float c2  = 2.f * scal[0];
    const float thr = scal[1];
    const int r0row = mw0 * 16 + ln;           // phase-1 A rows (per lane)
    const int r1row = r0row + 16;
    const int x0 = (r0row & 7) << 4, x1 = (r1row & 7) << 4;

    float tt_ = 1.f;
    for (int step = 0; step < NSTEPS; ++step) {
        // ======== phase 1: R = y W - in  (two 16x16 tiles per wave) ========
        f32x4 acc0 = { nin[0][0], nin[0][1], nin[0][2], nin[0][3] };
        f32x4 acc1 = { nin[1][0], nin[1][1], nin[1][2], nin[1][3] };
        #pragma unroll
        for (int c = 0; c < 8; ++c) {
            const int kb = c * 64 + l4 * 16;
            bf16x8 a0h = *(const bf16x8*)(yhb + r0row * 512 + (kb ^ x0));
            bf16x8 a0l = *(const bf16x8*)(ylb + r0row * 512 + (kb ^ x0));
            bf16x8 a1h = *(const bf16x8*)(yhb + r1row * 512 + (kb ^ x1));
            bf16x8 a1l = *(const bf16x8*)(ylb + r1row * 512 + (kb ^ x1));
            acc0 = __builtin_amdgcn_mfma_f32_16x16x32_bf16(a0h, wbh[c], acc0, 0, 0, 0);
            acc0 = __builtin_amdgcn_mfma_f32_16x16x32_bf16(a0l, wbh[c], acc0, 0, 0, 0);
            acc0 = __builtin_amdgcn_mfma_f32_16x16x32_bf16(a0h, wbl[c], acc0, 0, 0, 0);
            acc1 = __builtin_amdgcn_mfma_f32_16x16x32_bf16(a1h, wbh[c], acc1, 0, 0, 0);
            acc1 = __builtin_amdgcn_mfma_f32_16x16x32_bf16(a1l, wbh[c], acc1, 0, 0, 0);
            acc1 = __builtin_amdgcn_mfma_f32_16x16x32_bf16(a1h, wbl[c], acc1, 0, 0, 0);
        }
        #pragma unroll
        for (int s = 0; s < 2; ++s) {
            #pragma unroll
            for (int r = 0; r < 4; ++r) {
                int row = (mw0 + s) * 16 + l4 * 4 + r;
                int off = row * 128 + (((nw * 16 + ln) * 2) ^ ((row & 7) << 4));
                float v = s ? acc1[r] : acc0[r];
                unsigned short h = f2bf(v);
                *(unsigned short*)(rhb + off) = h;
                *(unsigned short*)(rlb + off) = f2bf(v - bf2f(h));
            }
        }
        __syncthreads();

        // ======== phase 2: g = R W^T  (2 m-tiles x 4 n-tiles per wave) ========
        f32x4 g2[2][4];
        #pragma unroll
        for (int s = 0; s < 2; ++s)
            #pragma unroll
            for (int q = 0; q < 4; ++q) g2[s][q] = (f32x4){0.f, 0.f, 0.f, 0.f};
        #pragma unroll
        for (int c = 0; c < 2; ++c) {
            const int kb = c * 64 + l4 * 16;
            const int r0 = (2 * mp) * 16 + ln;
            const int r1 = r0 + 16;
            const int rx = (ln & 7) << 4;
            bf16x8 rh0 = *(const bf16x8*)(rhb + r0 * 128 + (kb ^ rx));
            bf16x8 rl0 = *(const bf16x8*)(rlb + r0 * 128 + (kb ^ rx));
            bf16x8 rh1 = *(const bf16x8*)(rhb + r1 * 128 + (kb ^ rx));
            bf16x8 rl1 = *(const bf16x8*)(rlb + r1 * 128 + (kb ^ rx));
            #pragma unroll
            for (int q = 0; q < 4; ++q) {
                const int brow = (4 * nq + q) * 16 + ln;
                bf16x8 bh = *(const bf16x8*)(whb + brow * 128 + (kb ^ rx));
                bf16x8 bl = *(const bf16x8*)(wlb + brow * 128 + (kb ^ rx));
                g2[0][q] = __builtin_amdgcn_mfma_f32_16x16x32_bf16(rh0, bh, g2[0][q], 0, 0, 0);
                g2[0][q] = __builtin_amdgcn_mfma_f32_16x16x32_bf16(rl0, bh, g2[0][q], 0, 0, 0);
                g2[0][q] = __builtin_amdgcn_mfma_f32_16x16x32_bf16(rh0, bl, g2[0][q], 0, 0, 0);
                g2[1][q] = __builtin_amdgcn_mfma_f32_16x16x32_bf16(rh1, bh, g2[1][q], 0, 0, 0);
                g2[1][q] = __builtin_amdgcn_mfma_f32_16x16x32_bf16(rl1, bh, g2[1][q], 0, 0, 0);
                g2[1][q] = __builtin_amdgcn_mfma_f32_16x16x32_bf16(rh1, bl, g2[1][q], 0, 0, 0);
            }
        }

        // ======== update: prox + momentum, write y (bf16 hi/lo) ========
        const float t2v = 0.5f + 0.5f * sqrtf(1.f + 4.f * tt_ * tt_);
        const float mom = (tt_ - 1.f) / t2v;
        tt_ = t2v;
        #pragma unroll
        for (int s = 0; s < 2; ++s)
          #pragma unroll
          for (int q = 0; q < 4; ++q)
            #pragma unroll
            for (int r = 0; r < 4; ++r) {
                float u  = ym[s][q][r] - c2 * g2[s][q][r];
                float x2 = fmaxf(u - thr, 0.f) + fminf(u + thr, 0.f);
                float yn = x2 + mom * (x2 - xm[s][q][r]);
                xm[s][q][r] = x2; ym[s][q][r] = yn;
                int row = (2 * mp + s) * 16 + l4 * 4 + r;
                int cb  = ((4 * nq + q) * 16 + ln) * 2;
                int off = row * 512 + (cb ^ ((row & 7) << 4));
                unsigned short h = f2bf(yn);
                *(unsigned short*)(yhb + off) = h;
                *(unsigned short*)(ylb + off) = f2bf(yn - bf2f(h));
            }
        __syncthreads();
    }

    // ---- store X ----
    #pragma unroll
    for (int s = 0; s < 2; ++s)
      #pragma unroll
      for (int q = 0; q < 4; ++q)
        #pragma unroll
        for (int r = 0; r < 4; ++r)
            out[(size_t)(rb + (2 * mp + s) * 16 + l4 * 4 + r) * 256 + (4 * nq + q) * 16 + ln] = xm[s][q][r];
}

extern "C" void kernel_launch(void* const* d_in, const int* in_sizes, int n_in,
                              void* d_out, int out_size, void* d_ws, size_t ws_size,
                              hipStream_t stream) {
    (void)in_sizes; (void)n_in; (void)d_ws; (void)ws_size; (void)out_size;
    const float* inp = (const float*)d_in[0];   // [16384, 64]
    const float* Wg  = (const float*)d_in[1];   // [256, 64]
    const float* X0  = (const float*)d_in[2];   // [16384, 256]
    float* outp      = (float*)d_out;           // [16384, 256]
    fista9<<<16384 / 64, NTH, 0, stream>>>(inp, Wg, X0, outp);
}

// Round 10
// 479.819 us; speedup vs baseline: 2.5812x; 1.1503x over previous
//
#include <hip/hip_runtime.h>
#include <hip/hip_bf16.h>

#define NTH     512
#define NSTEPS  100
#define PITERS  50
#define LAMBDAV 0.1f

typedef __bf16 bf16x8 __attribute__((ext_vector_type(8)));
typedef float  f32x4  __attribute__((ext_vector_type(4)));

// R10 = R9 champion + (a) native bf16 casts (compiler emits cvt_pk; R6-proven)
//     + (b) transposed phase 2: g^T = W * R^T.
//   A = W from whb/wlb rows (same addresses R9 read as B-frags),
//   B = R^T from row-major rhb/rlb (B-frag: lane ln -> R[16rt+ln][8*l4+t+32kc],
//       contiguous 16B). D-layout: thread owns g^T[j=32w+16dt+4l4+r][row=16rt+ln]
//   -> 4 CONSECUTIVE y columns per tile -> packed ds_write_b64 y-writes
//      (16 vs R9's 64 scalar b16) and float4 X0/out access.
// LDS map (identical to R2/R9, 147456 B):
//   yh [64][256] bf16 @0      stride 512   yl @32768
//   whb[256][64] bf16 @65536  stride 128   wlb @98304
//   rhb[64][64]  bf16 @131072 stride 128   rlb @139264
//   wst fp32 [256][64] stride 256 overlays yh/yl during init.
// Persistent regs = 136 (wbh/wbl 64 + xm 32 + ym 32 + nin 8) — R9-proven.

__global__ __launch_bounds__(NTH, 2)
void fista10(const float* __restrict__ inp, const float* __restrict__ Wg,
             const float* __restrict__ X0, float* __restrict__ out)
{
    __shared__ __align__(16) char lds[147456];
    __shared__ __align__(16) float vf[256];
    __shared__ __align__(16) float up[256];
    __shared__ __align__(16) float uf[64];
    __shared__ float red[16];
    __shared__ float scal[2];

    char* const yhb = lds;
    char* const ylb = lds + 32768;
    char* const whb = lds + 65536;
    char* const wlb = lds + 98304;
    char* const rhb = lds + 131072;
    char* const rlb = lds + 139264;
    char* const wst = lds;            // fp32 staging overlay

    const int tid  = threadIdx.x;
    const int w    = tid >> 6;
    const int lane = tid & 63;
    const int l4   = lane >> 4;       // 0..3
    const int ln   = lane & 15;       // 0..15
    const int rb   = blockIdx.x * 64;

    // phase-1 (unchanged R9): wave -> n-tile nw, m-tiles {mw0, mw0+1}
    const int nw  = w & 3;
    const int mw0 = (w >> 2) * 2;
    // phase-2': wave -> dout-tiles {2w, 2w+1}, all 4 row-tiles

    // ---- stage W fp32 into LDS (swizzled) + bf16 hi/lo planes ----
    #pragma unroll
    for (int i = 0; i < 8; ++i) {
        int wi = (tid + i * NTH) * 4;
        int j = wi >> 6, k = wi & 63;
        f32x4 v = *(const f32x4*)&Wg[wi];
        *(f32x4*)(wst + j * 256 + ((k * 4) ^ ((j & 7) << 4))) = v;
    }
    for (int i = tid; i < 256 * 64; i += NTH) {
        int j = i >> 6, k = i & 63;
        float wv = Wg[i];
        __bf16 h = (__bf16)wv;
        int off = j * 128 + ((k * 2) ^ ((j & 7) << 4));
        *(__bf16*)(whb + off) = h;
        *(__bf16*)(wlb + off) = (__bf16)(wv - (float)h);
    }

    // ---- per-thread constants ----
    float nin[2][4];                           // -in, phase-1 D layout (unchanged)
    #pragma unroll
    for (int s = 0; s < 2; ++s)
        #pragma unroll
        for (int r = 0; r < 4; ++r)
            nin[s][r] = -inp[(size_t)(rb + (mw0 + s) * 16 + l4 * 4 + r) * 64 + nw * 16 + ln];

    float xm[2][4][4], ym[2][4][4];            // phase-2' D layout: [dt][rt][r]
    #pragma unroll
    for (int dt = 0; dt < 2; ++dt)
      #pragma unroll
      for (int rt = 0; rt < 4; ++rt) {
          f32x4 x = *(const f32x4*)&X0[(size_t)(rb + 16 * rt + ln) * 256 + 32 * w + 16 * dt + 4 * l4];
          #pragma unroll
          for (int r = 0; r < 4; ++r) { xm[dt][rt][r] = x[r]; ym[dt][rt][r] = x[r]; }
      }

    if (tid < 256) vf[tid] = 0.0625f;          // ones/sqrt(256)
    __syncthreads();

    // ---- Lipschitz: 50 power iterations of Q = 2 W W^T (R2-verified) ----
    for (int it = 0; it <= PITERS; ++it) {
        if (tid < 256) {
            int col = tid & 63, jq = tid >> 6;
            float s = 0.f;
            #pragma unroll 4
            for (int j = jq * 64; j < jq * 64 + 64; ++j)
                s += vf[j] * *(const float*)(wst + j * 256 + ((col * 4) ^ ((j & 7) << 4)));
            up[tid] = s;
        }
        __syncthreads();
        if (tid < 64) uf[tid] = up[tid] + up[tid + 64] + up[tid + 128] + up[tid + 192];
        __syncthreads();
        float w2 = 0.f;
        if (tid < 256) {
            float s = 0.f;
            #pragma unroll
            for (int kc = 0; kc < 64; kc += 4) {
                f32x4 wv = *(const f32x4*)(wst + tid * 256 + ((kc * 4) ^ ((tid & 7) << 4)));
                f32x4 u4 = *(const f32x4*)&uf[kc];
                s += wv.x * u4.x + wv.y * u4.y + wv.z * u4.z + wv.w * u4.w;
            }
            w2 = 2.f * s;
        }
        float sq = (tid < 256) ? ((it == PITERS) ? vf[tid] * w2 : w2 * w2) : 0.f;
        #pragma unroll
        for (int off = 32; off >= 1; off >>= 1) sq += __shfl_down(sq, off);
        if (tid < 256 && lane == 0) red[tid >> 6] = sq;
        __syncthreads();
        float tot = red[0] + red[1] + red[2] + red[3];
        if (it < PITERS) {
            if (tid < 256) vf[tid] = w2 * (1.f / sqrtf(tot));
        } else if (tid == 0) {
            scal[0] = 1.f / tot;               // invL (Rayleigh quotient)
            scal[1] = LAMBDAV / tot;           // thr
        }
        __syncthreads();
    }

    // ---- phase-1 B fragments (W columns nw*16..+15, K=256) -> registers ----
    bf16x8 wbh[8], wbl[8];
    #pragma unroll
    for (int c = 0; c < 8; ++c) {
        bf16x8 ph{}, pl{};
        #pragma unroll
        for (int t = 0; t < 8; ++t) {
            int j = 32 * c + 8 * l4 + t;
            float wv = *(const float*)(wst + j * 256 + (((nw * 16 + ln) * 4) ^ ((j & 7) << 4)));
            __bf16 h = (__bf16)wv;
            ph[t] = h; pl[t] = (__bf16)(wv - (float)h);
        }
        wbh[c] = ph; wbl[c] = pl;
    }
    __syncthreads();   // done with fp32 W staging; y region is now free

    // ---- y0 = X0 into LDS (bf16 hi/lo, packed b64 writes) ----
    #pragma unroll
    for (int dt = 0; dt < 2; ++dt)
      #pragma unroll
      for (int rt = 0; rt < 4; ++rt) {
          const int row  = 16 * rt + ln;
          const int colb = (32 * w + 16 * dt + 4 * l4) * 2;
          unsigned short hb[4], lb[4];
          #pragma unroll
          for (int r = 0; r < 4; ++r) {
              float v = ym[dt][rt][r];
              __bf16 h = (__bf16)v;
              hb[r] = __builtin_bit_cast(unsigned short, h);
              lb[r] = __builtin_bit_cast(unsigned short, (__bf16)(v - (float)h));
          }
          const int off = row * 512 + (colb ^ ((row & 7) << 4));
          uint2 H, L;
          H.x = hb[0] | ((unsigned)hb[1] << 16); H.y = hb[2] | ((unsigned)hb[3] << 16);
          L.x = lb[0] | ((unsigned)lb[1] << 16); L.y = lb[2] | ((unsigned)lb[3] << 16);
          *(uint2*)(yhb + off) = H;
          *(uint2*)(ylb + off) = L;
      }
    __syncthreads();

    const float c2  = 2.f * scal[0];
    const float thr = scal[1];
    const int r0row = mw0 * 16 + ln;           // phase-1 A rows (per lane)
    const int r1row = r0row + 16;
    const int x0 = (r0row & 7) << 4, x1 = (r1row & 7) << 4;
    const int rx = (ln & 7) << 4;              // shared swizzle for 128B-stride planes

    float tt_ = 1.f;
    for (int step = 0; step < NSTEPS; ++step) {
        // ======== phase 1 (unchanged): R = y W - in ========
        f32x4 acc0 = { nin[0][0], nin[0][1], nin[0][2], nin[0][3] };
        f32x4 acc1 = { nin[1][0], nin[1][1], nin[1][2], nin[1][3] };
        #pragma unroll
        for (int c = 0; c < 8; ++c) {
            const int kb = c * 64 + l4 * 16;
            bf16x8 a0h = *(const bf16x8*)(yhb + r0row * 512 + (kb ^ x0));
            bf16x8 a0l = *(const bf16x8*)(ylb + r0row * 512 + (kb ^ x0));
            bf16x8 a1h = *(const bf16x8*)(yhb + r1row * 512 + (kb ^ x1));
            bf16x8 a1l = *(const bf16x8*)(ylb + r1row * 512 + (kb ^ x1));
            acc0 = __builtin_amdgcn_mfma_f32_16x16x32_bf16(a0h, wbh[c], acc0, 0, 0, 0);
            acc0 = __builtin_amdgcn_mfma_f32_16x16x32_bf16(a0l, wbh[c], acc0, 0, 0, 0);
            acc0 = __builtin_amdgcn_mfma_f32_16x16x32_bf16(a0h, wbl[c], acc0, 0, 0, 0);
            acc1 = __builtin_amdgcn_mfma_f32_16x16x32_bf16(a1h, wbh[c], acc1, 0, 0, 0);
            acc1 = __builtin_amdgcn_mfma_f32_16x16x32_bf16(a1l, wbh[c], acc1, 0, 0, 0);
            acc1 = __builtin_amdgcn_mfma_f32_16x16x32_bf16(a1h, wbl[c], acc1, 0, 0, 0);
        }
        #pragma unroll
        for (int s = 0; s < 2; ++s) {
            #pragma unroll
            for (int r = 0; r < 4; ++r) {
                int row = (mw0 + s) * 16 + l4 * 4 + r;
                int off = row * 128 + (((nw * 16 + ln) * 2) ^ ((row & 7) << 4));
                float v = s ? acc1[r] : acc0[r];
                __bf16 h = (__bf16)v;
                *(__bf16*)(rhb + off) = h;
                *(__bf16*)(rlb + off) = (__bf16)(v - (float)h);
            }
        }
        __syncthreads();

        // ======== phase 2': g^T = W R^T  (2 dout-tiles x 4 row-tiles) ========
        f32x4 gt[2][4];
        #pragma unroll
        for (int dt = 0; dt < 2; ++dt)
            #pragma unroll
            for (int rt = 0; rt < 4; ++rt) gt[dt][rt] = (f32x4){0.f, 0.f, 0.f, 0.f};
        #pragma unroll
        for (int kc = 0; kc < 2; ++kc) {
            const int kb = kc * 64 + l4 * 16;
            const int j0 = (32 * w + ln) * 128;
            const int j1 = (32 * w + 16 + ln) * 128;
            bf16x8 ah0 = *(const bf16x8*)(whb + j0 + (kb ^ rx));
            bf16x8 al0 = *(const bf16x8*)(wlb + j0 + (kb ^ rx));
            bf16x8 ah1 = *(const bf16x8*)(whb + j1 + (kb ^ rx));
            bf16x8 al1 = *(const bf16x8*)(wlb + j1 + (kb ^ rx));
            #pragma unroll
            for (int rt = 0; rt < 4; ++rt) {
                const int rr = (16 * rt + ln) * 128;
                bf16x8 bh = *(const bf16x8*)(rhb + rr + (kb ^ rx));
                bf16x8 bl = *(const bf16x8*)(rlb + rr + (kb ^ rx));
                gt[0][rt] = __builtin_amdgcn_mfma_f32_16x16x32_bf16(ah0, bh, gt[0][rt], 0, 0, 0);
                gt[0][rt] = __builtin_amdgcn_mfma_f32_16x16x32_bf16(al0, bh, gt[0][rt], 0, 0, 0);
                gt[0][rt] = __builtin_amdgcn_mfma_f32_16x16x32_bf16(ah0, bl, gt[0][rt], 0, 0, 0);
                gt[1][rt] = __builtin_amdgcn_mfma_f32_16x16x32_bf16(ah1, bh, gt[1][rt], 0, 0, 0);
                gt[1][rt] = __builtin_amdgcn_mfma_f32_16x16x32_bf16(al1, bh, gt[1][rt], 0, 0, 0);
                gt[1][rt] = __builtin_amdgcn_mfma_f32_16x16x32_bf16(ah1, bl, gt[1][rt], 0, 0, 0);
            }
        }

        // ======== update: prox + momentum; packed b64 y-writes ========
        const float t2v = 0.5f + 0.5f * sqrtf(1.f + 4.f * tt_ * tt_);
        const float mom = (tt_ - 1.f) / t2v;
        tt_ = t2v;
        #pragma unroll
        for (int dt = 0; dt < 2; ++dt)
          #pragma unroll
          for (int rt = 0; rt < 4; ++rt) {
              const int row  = 16 * rt + ln;
              const int colb = (32 * w + 16 * dt + 4 * l4) * 2;
              unsigned short hb[4], lb[4];
              #pragma unroll
              for (int r = 0; r < 4; ++r) {
                  float u  = ym[dt][rt][r] - c2 * gt[dt][rt][r];
                  float x2 = fmaxf(u - thr, 0.f) + fminf(u + thr, 0.f);
                  float yn = x2 + mom * (x2 - xm[dt][rt][r]);
                  xm[dt][rt][r] = x2; ym[dt][rt][r] = yn;
                  __bf16 h = (__bf16)yn;
                  hb[r] = __builtin_bit_cast(unsigned short, h);
                  lb[r] = __builtin_bit_cast(unsigned short, (__bf16)(yn - (float)h));
              }
              const int off = row * 512 + (colb ^ ((row & 7) << 4));
              uint2 H, L;
              H.x = hb[0] | ((unsigned)hb[1] << 16); H.y = hb[2] | ((unsigned)hb[3] << 16);
              L.x = lb[0] | ((unsigned)lb[1] << 16); L.y = lb[2] | ((unsigned)lb[3] << 16);
              *(uint2*)(yhb + off) = H;
              *(uint2*)(ylb + off) = L;
          }
        __syncthreads();
    }

    // ---- store X (float4) ----
    #pragma unroll
    for (int dt = 0; dt < 2; ++dt)
      #pragma unroll
      for (int rt = 0; rt < 4; ++rt) {
          f32x4 o = { xm[dt][rt][0], xm[dt][rt][1], xm[dt][rt][2], xm[dt][rt][3] };
          *(f32x4*)&out[(size_t)(rb + 16 * rt + ln) * 256 + 32 * w + 16 * dt + 4 * l4] = o;
      }
}

extern "C" void kernel_launch(void* const* d_in, const int* in_sizes, int n_in,
                              void* d_out, int out_size, void* d_ws, size_t ws_size,
                              hipStream_t stream) {
    (void)in_sizes; (void)n_in; (void)d_ws; (void)ws_size; (void)out_size;
    const float* inp = (const float*)d_in[0];   // [16384, 64]
    const float* Wg  = (const float*)d_in[1];   // [256, 64]
    const float* X0  = (const float*)d_in[2];   // [16384, 256]
    float* outp      = (float*)d_out;           // [16384, 256]
    fista10<<<16384 / 64, NTH, 0, stream>>>(inp, Wg, X0, outp);
}